// Round 3
// baseline (47.614 us; speedup 1.0000x reference)
//
#include <hip/hip_runtime.h>

// score[e] = dot(h[src[e]], h[dst[e]]), D=32.
// h converted once to bf16 in d_ws (6.4 MB ~ per-XCD L2) to halve gather bytes.
// Edge kernel: 1 lane per edge -> 2 coalesced index loads + 8 independent 16-B
// gathers (full 64-B src row + 64-B dst row), dot fully in-lane (no shuffles),
// coalesced f32 store. Maximizes memory-level parallelism per wave.

constexpr int D_FEAT = 32;

static __device__ __forceinline__ float bf_lo(unsigned u) {
    return __uint_as_float(u << 16);
}
static __device__ __forceinline__ float bf_hi(unsigned u) {
    return __uint_as_float(u & 0xffff0000u);
}
static __device__ __forceinline__ unsigned short f2bf_rne(float f) {
    unsigned u = __float_as_uint(f);
    u = (u + 0x7fffu + ((u >> 16) & 1u)) >> 16;  // round-nearest-even
    return (unsigned short)u;
}

static __device__ __forceinline__ float dot8(uint4 a, uint4 b) {
    float acc;
    acc  = bf_lo(a.x) * bf_lo(b.x) + bf_hi(a.x) * bf_hi(b.x);
    acc += bf_lo(a.y) * bf_lo(b.y) + bf_hi(a.y) * bf_hi(b.y);
    acc += bf_lo(a.z) * bf_lo(b.z) + bf_hi(a.z) * bf_hi(b.z);
    acc += bf_lo(a.w) * bf_lo(b.w) + bf_hi(a.w) * bf_hi(b.w);
    return acc;
}

__global__ void __launch_bounds__(256) convert_h_bf16(
    const float4* __restrict__ h4, ushort4* __restrict__ hb4, int n4)
{
    int i = blockIdx.x * blockDim.x + threadIdx.x;
    const int stride = gridDim.x * blockDim.x;
    for (; i < n4; i += stride) {
        const float4 v = h4[i];
        ushort4 o;
        o.x = f2bf_rne(v.x);
        o.y = f2bf_rne(v.y);
        o.z = f2bf_rne(v.z);
        o.w = f2bf_rne(v.w);
        hb4[i] = o;
    }
}

__global__ void __launch_bounds__(256) edge_dot_bf16(
    const unsigned short* __restrict__ hb,
    const int* __restrict__ src,
    const int* __restrict__ dst,
    float* __restrict__ out,
    int n_edges)
{
    int i = blockIdx.x * blockDim.x + threadIdx.x;
    const int stride = gridDim.x * blockDim.x;
    for (int e = i; e < n_edges; e += stride) {
        const int s = src[e];
        const int d = dst[e];
        const uint4* pa = reinterpret_cast<const uint4*>(hb + (size_t)s * D_FEAT);
        const uint4* pb = reinterpret_cast<const uint4*>(hb + (size_t)d * D_FEAT);
        // 8 independent 16-B gathers; compiler clusters them under one waitcnt.
        const uint4 a0 = pa[0], a1 = pa[1], a2 = pa[2], a3 = pa[3];
        const uint4 b0 = pb[0], b1 = pb[1], b2 = pb[2], b3 = pb[3];
        float acc = dot8(a0, b0);
        acc += dot8(a1, b1);
        acc += dot8(a2, b2);
        acc += dot8(a3, b3);
        out[e] = acc;
    }
}

// f32 fallback (if ws too small for bf16 copy of h)
__global__ void __launch_bounds__(256) edge_dot_f32(
    const float* __restrict__ h,
    const int* __restrict__ src,
    const int* __restrict__ dst,
    float* __restrict__ out,
    int n_edges)
{
    int i = blockIdx.x * blockDim.x + threadIdx.x;
    const int stride = gridDim.x * blockDim.x;
    for (int e = i; e < n_edges; e += stride) {
        const int s = src[e];
        const int d = dst[e];
        const float4* pa = reinterpret_cast<const float4*>(h + (size_t)s * D_FEAT);
        const float4* pb = reinterpret_cast<const float4*>(h + (size_t)d * D_FEAT);
        float acc = 0.f;
        #pragma unroll
        for (int k = 0; k < 8; ++k) {
            const float4 a = pa[k];
            const float4 b = pb[k];
            acc += a.x * b.x + a.y * b.y + a.z * b.z + a.w * b.w;
        }
        out[e] = acc;
    }
}

extern "C" void kernel_launch(void* const* d_in, const int* in_sizes, int n_in,
                              void* d_out, int out_size, void* d_ws, size_t ws_size,
                              hipStream_t stream) {
    const float* h   = (const float*)d_in[0];
    const int*   src = (const int*)d_in[1];
    const int*   dst = (const int*)d_in[2];
    float*       out = (float*)d_out;
    const int n_h     = in_sizes[0];           // N_NODES * D_FEAT
    const int n_edges = in_sizes[1];

    const size_t need = (size_t)n_h * sizeof(unsigned short);
    if (ws_size >= need) {
        unsigned short* hb = (unsigned short*)d_ws;
        const int n4 = n_h / 4;
        convert_h_bf16<<<2048, 256, 0, stream>>>(
            (const float4*)h, (ushort4*)hb, n4);
        edge_dot_bf16<<<2048, 256, 0, stream>>>(hb, src, dst, out, n_edges);
    } else {
        edge_dot_f32<<<2048, 256, 0, stream>>>(h, src, dst, out, n_edges);
    }
}

// Round 4
// 41.688 us; speedup vs baseline: 1.1422x; 1.1422x over previous
//
#include <hip/hip_runtime.h>

// score[e] = dot(h[src[e]], h[dst[e]]), D=32.
// h converted once to bf16 in d_ws (6.4 MB) to halve gather bytes; rows = 64 B
// = one cache line. Edge kernel: 4 lanes/edge (16 B per lane, row covered by
// one wave-instruction slice of 16 distinct lines), UNROLL x2 edges per group:
// issue both edges' index loads, then all 4 gathers, before any compute ->
// 4 outstanding gathers per lane (2x round-2 MLP), same divergence profile.

constexpr int D_FEAT = 32;

static __device__ __forceinline__ float bf_lo(unsigned u) {
    return __uint_as_float(u << 16);
}
static __device__ __forceinline__ float bf_hi(unsigned u) {
    return __uint_as_float(u & 0xffff0000u);
}
static __device__ __forceinline__ unsigned short f2bf_rne(float f) {
    unsigned u = __float_as_uint(f);
    u = (u + 0x7fffu + ((u >> 16) & 1u)) >> 16;  // round-nearest-even
    return (unsigned short)u;
}

static __device__ __forceinline__ float dot8(uint4 a, uint4 b) {
    float acc;
    acc  = bf_lo(a.x) * bf_lo(b.x) + bf_hi(a.x) * bf_hi(b.x);
    acc += bf_lo(a.y) * bf_lo(b.y) + bf_hi(a.y) * bf_hi(b.y);
    acc += bf_lo(a.z) * bf_lo(b.z) + bf_hi(a.z) * bf_hi(b.z);
    acc += bf_lo(a.w) * bf_lo(b.w) + bf_hi(a.w) * bf_hi(b.w);
    return acc;
}

__global__ void __launch_bounds__(256) convert_h_bf16(
    const float4* __restrict__ h4, ushort4* __restrict__ hb4, int n4)
{
    int i = blockIdx.x * blockDim.x + threadIdx.x;
    const int stride = gridDim.x * blockDim.x;
    for (; i < n4; i += stride) {
        const float4 v = h4[i];
        ushort4 o;
        o.x = f2bf_rne(v.x);
        o.y = f2bf_rne(v.y);
        o.z = f2bf_rne(v.z);
        o.w = f2bf_rne(v.w);
        hb4[i] = o;
    }
}

__global__ void __launch_bounds__(256) edge_dot_bf16(
    const unsigned short* __restrict__ hb,
    const int* __restrict__ src,
    const int* __restrict__ dst,
    float* __restrict__ out,
    int n_edges)
{
    const int g = threadIdx.x & 3;  // lane-in-group: 4 lanes/edge, 16 B each
    const int group = (blockIdx.x * blockDim.x + threadIdx.x) >> 2;
    const int n_groups = (gridDim.x * blockDim.x) >> 2;

    for (int e0 = group; e0 < n_edges; e0 += 2 * n_groups) {
        const int e1 = e0 + n_groups;
        const bool has1 = e1 < n_edges;

        // index loads for both edges first (independent)
        const int s0 = src[e0];
        const int d0 = dst[e0];
        const int s1 = has1 ? src[e1] : s0;
        const int d1 = has1 ? dst[e1] : d0;

        // all four 16-B gathers issued back-to-back (one waitcnt covers all)
        const uint4 a0 = reinterpret_cast<const uint4*>(hb + (size_t)s0 * D_FEAT)[g];
        const uint4 b0 = reinterpret_cast<const uint4*>(hb + (size_t)d0 * D_FEAT)[g];
        const uint4 a1 = reinterpret_cast<const uint4*>(hb + (size_t)s1 * D_FEAT)[g];
        const uint4 b1 = reinterpret_cast<const uint4*>(hb + (size_t)d1 * D_FEAT)[g];

        float acc0 = dot8(a0, b0);
        float acc1 = dot8(a1, b1);
        acc0 += __shfl_xor(acc0, 1);
        acc0 += __shfl_xor(acc0, 2);
        acc1 += __shfl_xor(acc1, 1);
        acc1 += __shfl_xor(acc1, 2);
        if (g == 0) {
            out[e0] = acc0;
            if (has1) out[e1] = acc1;
        }
    }
}

// f32 fallback (if ws too small for bf16 copy of h)
__global__ void __launch_bounds__(256) edge_dot_f32(
    const float* __restrict__ h,
    const int* __restrict__ src,
    const int* __restrict__ dst,
    float* __restrict__ out,
    int n_edges)
{
    const int g = threadIdx.x & 7;
    const int group = (blockIdx.x * blockDim.x + threadIdx.x) >> 3;
    const int n_groups = (gridDim.x * blockDim.x) >> 3;
    for (int e = group; e < n_edges; e += n_groups) {
        const int s = src[e];
        const int d = dst[e];
        const float4 a = reinterpret_cast<const float4*>(h + (size_t)s * D_FEAT)[g];
        const float4 b = reinterpret_cast<const float4*>(h + (size_t)d * D_FEAT)[g];
        float acc = a.x * b.x + a.y * b.y + a.z * b.z + a.w * b.w;
        acc += __shfl_xor(acc, 1);
        acc += __shfl_xor(acc, 2);
        acc += __shfl_xor(acc, 4);
        if (g == 0) out[e] = acc;
    }
}

extern "C" void kernel_launch(void* const* d_in, const int* in_sizes, int n_in,
                              void* d_out, int out_size, void* d_ws, size_t ws_size,
                              hipStream_t stream) {
    const float* h   = (const float*)d_in[0];
    const int*   src = (const int*)d_in[1];
    const int*   dst = (const int*)d_in[2];
    float*       out = (float*)d_out;
    const int n_h     = in_sizes[0];           // N_NODES * D_FEAT
    const int n_edges = in_sizes[1];

    const size_t need = (size_t)n_h * sizeof(unsigned short);
    if (ws_size >= need) {
        unsigned short* hb = (unsigned short*)d_ws;
        const int n4 = n_h / 4;
        convert_h_bf16<<<2048, 256, 0, stream>>>(
            (const float4*)h, (ushort4*)hb, n4);
        edge_dot_bf16<<<2048, 256, 0, stream>>>(hb, src, dst, out, n_edges);
    } else {
        edge_dot_f32<<<2048, 256, 0, stream>>>(h, src, dst, out, n_edges);
    }
}